// Round 2
// baseline (348.013 us; speedup 1.0000x reference)
//
#include <hip/hip_runtime.h>

// Histogram1D: triangular-kernel soft histogram, 100 bins over [0,1], row-normalized.
// x: [32, 1048576] f32. out: [32, 100] f32.
// Each element contributes to exactly 2 adjacent bins (in units of DELTA=0.01):
//   u = x*100 - 0.5; i0 = floor(u); w = u - i0
//   bin i0   += (1-w)   [skipped if i0 < 0]
//   bin i0+1 += w       [skipped if i0 > 98]
//
// Round-2 change: bank-replicated per-wave LDS histograms. Layout
// sh[wave][bin][replica=32]; lane uses replica lane&31 -> its ds_add_f32
// always lands in bank (lane&31): conflict-free (2 lanes/bank is free),
// no same-address serialization except the rare lane/lane+32 same-bin case.

#define BINS 100
#define BATCH 32
#define NPER 1048576
#define TPB 256
#define BLOCKS_PER_ROW 16
#define CHUNK (NPER / BLOCKS_PER_ROW)       // 65536 elements per block
#define F4_PER_THREAD (CHUNK / 4 / TPB)     // 64 float4 per thread
#define HWORDS (4 * BINS * 32)              // 12800 floats = 51.2 KB

__global__ __launch_bounds__(TPB) void hist_kernel(const float* __restrict__ x,
                                                   float* __restrict__ acc) {
    __shared__ float sh[HWORDS];            // [wave][bin][replica]
    const int tid = threadIdx.x;
    for (int i = tid; i < HWORDS; i += TPB) sh[i] = 0.0f;
    __syncthreads();

    const int row  = blockIdx.y;
    const int blk  = blockIdx.x;
    const int wave = tid >> 6;
    float* hist = sh + wave * (BINS * 32) + (tid & 31);   // index by bin*32

    const float4* src = reinterpret_cast<const float4*>(
        x + (size_t)row * NPER + (size_t)blk * CHUNK);

#pragma unroll 8
    for (int k = 0; k < F4_PER_THREAD; ++k) {
        float4 v = src[k * TPB + tid];
        float vv[4] = {v.x, v.y, v.z, v.w};
#pragma unroll
        for (int e = 0; e < 4; ++e) {
            float u  = vv[e] * (float)BINS - 0.5f;
            float fi = floorf(u);            // i0 in [-1, 99]
            float w  = u - fi;               // [0,1)
            int   i0 = (int)fi;
            if (i0 >= 0)       unsafeAtomicAdd(&hist[i0 * 32], 1.0f - w);
            if (i0 < BINS - 1) unsafeAtomicAdd(&hist[(i0 + 1) * 32], w);
        }
    }
    __syncthreads();

    // Reduce 4 waves x 32 replicas per bin. Rotated replica index keeps the
    // 64 active lanes on distinct banks ((j+bin)&31 varies across lanes).
    if (tid < BINS) {
        float s = 0.0f;
#pragma unroll 4
        for (int j = 0; j < 128; ++j) {
            int w = j >> 5;
            int r = (j + tid) & 31;
            s += sh[w * (BINS * 32) + tid * 32 + r];
        }
        unsafeAtomicAdd(&acc[row * BINS + tid], s);
    }
}

// In-place normalize: acc (w-units) -> DELTA*acc / (DELTA*rowsum + EPS).
__global__ __launch_bounds__(64) void norm_kernel(float* __restrict__ acc) {
    const int row = blockIdx.x;
    const int t   = threadIdx.x;
    float v0 = (t < BINS)      ? acc[row * BINS + t]      : 0.0f;
    float v1 = (t + 64 < BINS) ? acc[row * BINS + t + 64] : 0.0f;
    float s  = v0 + v1;
#pragma unroll
    for (int off = 32; off > 0; off >>= 1) s += __shfl_down(s, off);
    s = __shfl(s, 0);
    const float DELTA = 0.01f;
    const float inv_denom = 1.0f / (DELTA * s + 1e-5f);
    if (t < BINS)      acc[row * BINS + t]      = (DELTA * v0) * inv_denom;
    if (t + 64 < BINS) acc[row * BINS + t + 64] = (DELTA * v1) * inv_denom;
}

extern "C" void kernel_launch(void* const* d_in, const int* in_sizes, int n_in,
                              void* d_out, int out_size, void* d_ws, size_t ws_size,
                              hipStream_t stream) {
    const float* x = (const float*)d_in[0];
    float* out = (float*)d_out;   // accumulator, normalized in place

    hipMemsetAsync(out, 0, (size_t)BATCH * BINS * sizeof(float), stream);
    hist_kernel<<<dim3(BLOCKS_PER_ROW, BATCH), TPB, 0, stream>>>(x, out);
    norm_kernel<<<BATCH, 64, 0, stream>>>(out);
}

// Round 3
// 53.686 us; speedup vs baseline: 6.4824x; 6.4824x over previous
//
#include <hip/hip_runtime.h>

// Histogram1D: triangular-kernel soft histogram, 100 bins over [0,1], row-normalized.
// x: [32, 1048576] f32. out: [32, 100] f32.
// u = x*100 - 0.5; i0 = floor(u); w = u - i0; bin i0 += (1-w); bin i0+1 += w
// (weights in units of DELTA; normalize applies DELTA so EPS matches the ref).
//
// Round-3 change: NO LDS ATOMICS. Rounds 1/2 proved scattered ds_add_f32
// costs ~3 cyc/lane (~200 cyc/wave-instr) regardless of bank layout — the
// atomic pipe serializes per lane. Instead each lane owns an exclusive
// histogram column: h[102][64] (bin-major, lane-minor) -> plain RMW, bank
// = lane&31 always (<=2 lanes/bank = free). Rows 0/101 are trash rows so
// edge clamping is branch-free. The per-element pair (rows r, r+1) is
// provably non-aliasing (+64 floats) so reads/writes pair into ds_read2/
// ds_write2; cross-element RMWs serialize per lane but 6 waves/CU overlap.

#define BINS 100
#define HROWS 102                           // row 0 and row 101 catch clamped edges
#define BATCH 32
#define NPER 1048576
#define TPB 64                              // one wave per block
#define BLOCKS_PER_ROW 64
#define CHUNK (NPER / BLOCKS_PER_ROW)       // 16384 elements per block
#define F4_PER_LANE (CHUNK / 4 / TPB)       // 64 float4 loads per lane

__global__ __launch_bounds__(TPB) void hist_kernel(const float* __restrict__ x,
                                                   float* __restrict__ acc) {
    __shared__ float h[HROWS * 64];         // 25.5 KB -> 6 blocks/CU
    const int lane = threadIdx.x;

    for (int i = lane; i < HROWS * 64; i += TPB) h[i] = 0.0f;
    __syncthreads();

    const int row = blockIdx.y;
    const int blk = blockIdx.x;
    const float4* src = reinterpret_cast<const float4*>(
        x + (size_t)row * NPER + (size_t)blk * CHUNK);
    float* hl = h + lane;                   // this lane's exclusive column

#pragma unroll 4
    for (int k = 0; k < F4_PER_LANE; ++k) {
        float4 v = src[k * TPB + lane];
        float vv[4] = {v.x, v.y, v.z, v.w};
#pragma unroll
        for (int e = 0; e < 4; ++e) {
            float u  = vv[e] * (float)BINS - 0.5f;
            float fi = floorf(u);           // i0 in [-1, 99]
            float w  = u - fi;              // [0,1)
            int   r  = (int)fi + 1;         // 0..100; rows 0 & 101 are trash
            float* p = hl + (r << 6);
            float lo = p[0];                // rows r, r+1: provably distinct,
            float hi = p[64];               // compiler can pair (ds_read2_b32)
            p[0]  = lo + (1.0f - w);
            p[64] = hi + w;
        }
    }
    __syncthreads();

    // Reduce the 64 lane-columns per bin. Thread t handles bins t (and t+64).
    // Rotated column index keeps lanes on distinct banks (<=2/bank = free).
    for (int b = lane; b < BINS; b += TPB) {
        const float* r0 = h + (b + 1) * 64;
        float s = 0.0f;
#pragma unroll
        for (int j = 0; j < 64; ++j) s += r0[(j + lane) & 63];
        unsafeAtomicAdd(&acc[row * BINS + b], s);
    }
}

// In-place normalize: acc (w-units) -> DELTA*acc / (DELTA*rowsum + EPS).
__global__ __launch_bounds__(64) void norm_kernel(float* __restrict__ acc) {
    const int row = blockIdx.x;
    const int t   = threadIdx.x;
    float v0 = (t < BINS)      ? acc[row * BINS + t]      : 0.0f;
    float v1 = (t + 64 < BINS) ? acc[row * BINS + t + 64] : 0.0f;
    float s  = v0 + v1;
#pragma unroll
    for (int off = 32; off > 0; off >>= 1) s += __shfl_down(s, off);
    s = __shfl(s, 0);
    const float DELTA = 0.01f;
    const float inv_denom = 1.0f / (DELTA * s + 1e-5f);
    if (t < BINS)      acc[row * BINS + t]      = (DELTA * v0) * inv_denom;
    if (t + 64 < BINS) acc[row * BINS + t + 64] = (DELTA * v1) * inv_denom;
}

extern "C" void kernel_launch(void* const* d_in, const int* in_sizes, int n_in,
                              void* d_out, int out_size, void* d_ws, size_t ws_size,
                              hipStream_t stream) {
    const float* x = (const float*)d_in[0];
    float* out = (float*)d_out;   // accumulator, normalized in place

    hipMemsetAsync(out, 0, (size_t)BATCH * BINS * sizeof(float), stream);
    hist_kernel<<<dim3(BLOCKS_PER_ROW, BATCH), TPB, 0, stream>>>(x, out);
    norm_kernel<<<BATCH, 64, 0, stream>>>(out);
}

// Round 4
// 51.804 us; speedup vs baseline: 6.7179x; 1.0363x over previous
//
#include <hip/hip_runtime.h>
#include <hip/hip_fp16.h>

// Histogram1D: triangular-kernel soft histogram, 100 bins over [0,1], row-normalized.
// x: [32, 1048576] f32. out: [32, 100] f32.
//
// Round-4 reformulation: per element, u = x*100-0.5, i0 = floor(u), w = u-i0.
// Instead of scattering (1-w) to bin i0 and w to bin i0+1 (two rows), accumulate
//   N[r] += 1, W[r] += w   at the single row r = i0+1 in [0,100]
// and recover counts[b] = N[b+1] - W[b+1] + W[b] at reduce time (identical algebra).
// (W,N) packed as __half2 -> one ds_read_b32 + one ds_write_b32 per element.
// Each lane owns an exclusive column (cell = h[r*64+lane], bank = lane&31:
// conflict-free, no atomics). Two elements per latency window: both reads
// issued together; the only collision case is r_a==r_b, resolved by merging
// both increments into both write values (equal totals -> benign double write).
// fp16 safety: N is an exact small integer (<=256 < 2048); W cells average
// ~2.5 with ~2.5 adds -> per-bin error ~1e-6 normalized vs 2e-4 threshold.

#define BINS 100
#define ROWS 101                            // r = i0+1, i0 in [-1, 99]
#define BATCH 32
#define NPER 1048576
#define TPB 64                              // one wave per block
#define BLOCKS_PER_ROW 64
#define CHUNK (NPER / BLOCKS_PER_ROW)       // 16384 elements per block
#define F4_PER_LANE (CHUNK / 4 / TPB)       // 64 float4 loads per lane

__global__ __launch_bounds__(TPB) void hist_kernel(const float* __restrict__ x,
                                                   float* __restrict__ acc) {
    __shared__ __half2 h[ROWS * 64];        // [row][lane], cell = (W, N): 25.9 KB
    __shared__ float rsN[ROWS], rsW[ROWS];
    const int lane = threadIdx.x;

    const __half2 zero2 = __float2half2_rn(0.0f);
    for (int i = lane; i < ROWS * 64; i += TPB) h[i] = zero2;
    __syncthreads();

    const int row = blockIdx.y;
    const int blk = blockIdx.x;
    const float4* src = reinterpret_cast<const float4*>(
        x + (size_t)row * NPER + (size_t)blk * CHUNK);
    __half2* hl = h + lane;                 // this lane's exclusive column

#pragma unroll 4
    for (int k = 0; k < F4_PER_LANE; ++k) {
        float4 v = src[k * TPB + lane];
        float vv[4] = {v.x, v.y, v.z, v.w};
#pragma unroll
        for (int p = 0; p < 2; ++p) {       // two elements per step
            float a = vv[2 * p], b = vv[2 * p + 1];
            float ua = a * (float)BINS - 0.5f;
            float ub = b * (float)BINS - 0.5f;
            float fa = floorf(ua), fb = floorf(ub);
            int ra = (int)fa + 1;           // 0..100
            int rb = (int)fb + 1;
            __half2 va = __floats2half2_rn(ua - fa, 1.0f);   // (W += w, N += 1)
            __half2 vb = __floats2half2_rn(ub - fb, 1.0f);
            bool eq = (ra == rb);
            __half2 ta = __hadd2(va, eq ? vb : zero2);
            __half2 tb = __hadd2(vb, eq ? va : zero2);
            __half2 ca = hl[ra * 64];       // independent reads, one lgkm wait
            __half2 cb = hl[rb * 64];
            hl[ra * 64] = __hadd2(ca, ta);  // eq case: both writes carry the
            hl[rb * 64] = __hadd2(cb, tb);  // same merged total -> benign
        }
    }
    __syncthreads();

    // Per-row sums over the 64 lane-columns (rotated index: distinct banks).
    for (int r = lane; r < ROWS; r += TPB) {
        float sN = 0.0f, sW = 0.0f;
#pragma unroll
        for (int j = 0; j < 64; ++j) {
            float2 f = __half22float2(h[r * 64 + ((j + r) & 63)]);
            sW += f.x;
            sN += f.y;
        }
        rsN[r] = sN;
        rsW[r] = sW;
    }
    __syncthreads();

    for (int b = lane; b < BINS; b += TPB) {
        float cnt = rsN[b + 1] - rsW[b + 1] + rsW[b];
        unsafeAtomicAdd(&acc[row * BINS + b], cnt);
    }
}

// In-place normalize: acc (w-units) -> DELTA*acc / (DELTA*rowsum + EPS).
__global__ __launch_bounds__(64) void norm_kernel(float* __restrict__ acc) {
    const int row = blockIdx.x;
    const int t   = threadIdx.x;
    float v0 = (t < BINS)      ? acc[row * BINS + t]      : 0.0f;
    float v1 = (t + 64 < BINS) ? acc[row * BINS + t + 64] : 0.0f;
    float s  = v0 + v1;
#pragma unroll
    for (int off = 32; off > 0; off >>= 1) s += __shfl_down(s, off);
    s = __shfl(s, 0);
    const float DELTA = 0.01f;
    const float inv_denom = 1.0f / (DELTA * s + 1e-5f);
    if (t < BINS)      acc[row * BINS + t]      = (DELTA * v0) * inv_denom;
    if (t + 64 < BINS) acc[row * BINS + t + 64] = (DELTA * v1) * inv_denom;
}

extern "C" void kernel_launch(void* const* d_in, const int* in_sizes, int n_in,
                              void* d_out, int out_size, void* d_ws, size_t ws_size,
                              hipStream_t stream) {
    const float* x = (const float*)d_in[0];
    float* out = (float*)d_out;   // accumulator, normalized in place

    hipMemsetAsync(out, 0, (size_t)BATCH * BINS * sizeof(float), stream);
    hist_kernel<<<dim3(BLOCKS_PER_ROW, BATCH), TPB, 0, stream>>>(x, out);
    norm_kernel<<<BATCH, 64, 0, stream>>>(out);
}

// Round 5
// 42.556 us; speedup vs baseline: 8.1778x; 1.2173x over previous
//
#include <hip/hip_runtime.h>
#include <hip/hip_fp16.h>

// Histogram1D: triangular-kernel soft histogram, 100 bins over [0,1], row-normalized.
// x: [32, 1048576] f32. out: [32, 100] f32.
//
// Formulation (validated R3/R4): u = x*100-0.5, i0=floor(u), w=u-i0, r=i0+1 in [0,100];
// accumulate N[r] += 1, W[r] += w; counts[b] = N[b+1] - W[b+1] + W[b].
//
// Round-5 change: OCCUPANCY. R3/R4 were stuck at ~46us with 6 waves/CU
// (1.5/SIMD) — latency-bound, DS pipe ~4x idle. Now 4 lanes (a DPP quad)
// share one histogram column: per-wave hist = 16 cols x 101 rows x half2(W,N)
// = 6.5 KB; 4 waves/block = 25.9 KB -> 6 blocks/CU = 24 waves/CU (6/SIMD).
// Quad collisions are resolved in-register: each lane exchanges (r, inc)
// with its 3 quad partners via DPP quad_perm (VALU pipe, not DS) and
// computes total_i = sum of inc_j where r_j == r_i. Lanes with equal rows
// write EQUAL merged totals to the same address (benign); reads of the same
// address in one ds_read broadcast the same old value. Cross-step ordering
// is safe: all quad lanes are in the same wave and the DS pipe is in-order.

#define BINS 100
#define ROWS 101
#define BATCH 32
#define NPER 1048576
#define TPB 256
#define WAVES 4
#define COLS 16
#define BLOCKS_PER_ROW 64
#define CHUNK (NPER / BLOCKS_PER_ROW)     // 16384 elements per block
#define F4_PER_LANE (CHUNK / 4 / TPB)     // 16 float4 loads per thread

__global__ __launch_bounds__(TPB) void hist_kernel(const float* __restrict__ x,
                                                   float* __restrict__ acc) {
    __shared__ __half2 h[WAVES * COLS * ROWS];   // [wave][col][row], 25.9 KB
    __shared__ float rsW[ROWS], rsN[ROWS];
    const int tid  = threadIdx.x;
    const int wave = tid >> 6;
    const int col  = (tid & 63) >> 2;            // 4 lanes (DPP quad) per column

    const __half2 zero2 = __float2half2_rn(0.0f);
    for (int i = tid; i < WAVES * COLS * ROWS; i += TPB) h[i] = zero2;
    __syncthreads();

    const int row = blockIdx.y;
    const int blk = blockIdx.x;
    const float4* src = reinterpret_cast<const float4*>(
        x + (size_t)row * NPER + (size_t)blk * CHUNK);
    __half2* hcol = h + (wave * COLS + col) * ROWS;

#pragma unroll 4
    for (int k = 0; k < F4_PER_LANE; ++k) {
        float4 v = src[k * TPB + tid];
        float vv[4] = {v.x, v.y, v.z, v.w};
#pragma unroll
        for (int e = 0; e < 4; ++e) {
            float u  = vv[e] * (float)BINS - 0.5f;
            float fi = floorf(u);                 // i0 in [-1, 99]
            int   r  = (int)fi + 1;               // 0..100
            __half2 inc0 = __floats2half2_rn(u - fi, 1.0f);   // (W += w, N += 1)
            int iu0 = __builtin_bit_cast(int, inc0);
            __half2 tot = inc0;
            // quad merge: gather partners' ORIGINAL (r, inc) via DPP quad_perm
            {   // partner = lane ^ 1  (quad_perm [1,0,3,2] = 0xB1)
                int rj = __builtin_amdgcn_update_dpp(r,   r,   0xB1, 0xF, 0xF, false);
                int ij = __builtin_amdgcn_update_dpp(iu0, iu0, 0xB1, 0xF, 0xF, false);
                if (rj == r) tot = __hadd2(tot, __builtin_bit_cast(__half2, ij));
            }
            {   // partner = lane ^ 2  (quad_perm [2,3,0,1] = 0x4E)
                int rj = __builtin_amdgcn_update_dpp(r,   r,   0x4E, 0xF, 0xF, false);
                int ij = __builtin_amdgcn_update_dpp(iu0, iu0, 0x4E, 0xF, 0xF, false);
                if (rj == r) tot = __hadd2(tot, __builtin_bit_cast(__half2, ij));
            }
            {   // partner = lane ^ 3  (quad_perm [3,2,1,0] = 0x1B)
                int rj = __builtin_amdgcn_update_dpp(r,   r,   0x1B, 0xF, 0xF, false);
                int ij = __builtin_amdgcn_update_dpp(iu0, iu0, 0x1B, 0xF, 0xF, false);
                if (rj == r) tot = __hadd2(tot, __builtin_bit_cast(__half2, ij));
            }
            __half2 old = hcol[r];                // equal rows -> broadcast read,
            hcol[r] = __hadd2(old, tot);          // equal merged totals -> benign write
        }
    }
    __syncthreads();

    // Per-row sums over all 64 cells (4 waves x 16 cols). Lanes = consecutive
    // rows -> stride-1 dword reads, conflict-free.
    if (tid < ROWS) {
        float sW = 0.0f, sN = 0.0f;
#pragma unroll 8
        for (int j = 0; j < WAVES * COLS; ++j) {
            float2 f = __half22float2(h[j * ROWS + tid]);
            sW += f.x;
            sN += f.y;
        }
        rsW[tid] = sW;
        rsN[tid] = sN;
    }
    __syncthreads();

    if (tid < BINS) {
        float cnt = rsN[tid + 1] - rsW[tid + 1] + rsW[tid];
        unsafeAtomicAdd(&acc[row * BINS + tid], cnt);
    }
}

// In-place normalize: acc (w-units) -> DELTA*acc / (DELTA*rowsum + EPS).
__global__ __launch_bounds__(64) void norm_kernel(float* __restrict__ acc) {
    const int row = blockIdx.x;
    const int t   = threadIdx.x;
    float v0 = (t < BINS)      ? acc[row * BINS + t]      : 0.0f;
    float v1 = (t + 64 < BINS) ? acc[row * BINS + t + 64] : 0.0f;
    float s  = v0 + v1;
#pragma unroll
    for (int off = 32; off > 0; off >>= 1) s += __shfl_down(s, off);
    s = __shfl(s, 0);
    const float DELTA = 0.01f;
    const float inv_denom = 1.0f / (DELTA * s + 1e-5f);
    if (t < BINS)      acc[row * BINS + t]      = (DELTA * v0) * inv_denom;
    if (t + 64 < BINS) acc[row * BINS + t + 64] = (DELTA * v1) * inv_denom;
}

extern "C" void kernel_launch(void* const* d_in, const int* in_sizes, int n_in,
                              void* d_out, int out_size, void* d_ws, size_t ws_size,
                              hipStream_t stream) {
    const float* x = (const float*)d_in[0];
    float* out = (float*)d_out;   // accumulator, normalized in place

    hipMemsetAsync(out, 0, (size_t)BATCH * BINS * sizeof(float), stream);
    hist_kernel<<<dim3(BLOCKS_PER_ROW, BATCH), TPB, 0, stream>>>(x, out);
    norm_kernel<<<BATCH, 64, 0, stream>>>(out);
}